// Round 9
// baseline (312.937 us; speedup 1.0000x reference)
//
#include <hip/hip_runtime.h>
#include <hip/hip_bf16.h>

// DecoderLSTM: B=256, S=512, H=512, E=256, V=16000
#define B_ 256
#define S_ 512
#define H_ 512
#define E_ 256
#define V_ 16000

typedef __attribute__((ext_vector_type(4))) float f32x4_t;
typedef __attribute__((ext_vector_type(8))) short bf16x8_t;

__device__ __forceinline__ float bf2f(short s) {
    union { unsigned u; float f; } v; v.u = ((unsigned)(unsigned short)s) << 16;
    return v.f;
}

// packed f32->bf16 RNE, 1 inst per 2 elems (vs 5 per elem scalar)
__device__ __forceinline__ bf16x8_t pack8(f32x4_t a, f32x4_t b) {
    union { unsigned u[4]; bf16x8_t v; } o;
    asm("v_cvt_pk_bf16_f32 %0, %1, %2" : "=v"(o.u[0]) : "v"(a[0]), "v"(a[1]));
    asm("v_cvt_pk_bf16_f32 %0, %1, %2" : "=v"(o.u[1]) : "v"(a[2]), "v"(a[3]));
    asm("v_cvt_pk_bf16_f32 %0, %1, %2" : "=v"(o.u[2]) : "v"(b[0]), "v"(b[1]));
    asm("v_cvt_pk_bf16_f32 %0, %1, %2" : "=v"(o.u[3]) : "v"(b[2]), "v"(b[3]));
    return o.v;
}

__device__ __forceinline__ void cvt8(short* dst, const float* src) {
    f32x4_t a = *(const f32x4_t*)src;
    f32x4_t b = *(const f32x4_t*)(src + 4);
    *(bf16x8_t*)dst = pack8(a, b);
}

// tanh = 1 - 2/(exp(2x)+1): 5 flat VALU (mul,exp,add,rcp,fma), no clamp needed
// (exp overflow -> inf -> rcp -> 0 -> +1; underflow -> 0 -> -1; both correct).
__device__ __forceinline__ float tanh5(float x) {
    float e = __expf(2.f * x);
    return 1.f - 2.f * __builtin_amdgcn_rcpf(e + 1.f);
}

// LDS chunk swizzle: row has 64 16B-chunks; interleave chunk bits + XOR row.
__device__ __forceinline__ int physc(int c, int r) {
    return ((((c & 7) << 3) | (c >> 3)) ^ (r & 7));
}

// ---------------------------------------------------------------------------
// pack_w2: attn_W second half (W2) -> fragment-ordered bf16, 16-wave layout.
// chunk c = ((kk*16 + w)*2 + nf)*64 + lane holds 8 bf16 of
//   W2[col = w*32+nf*16+(lane&15)][k = kk*32+(lane>>4)*8 + j]
// ---------------------------------------------------------------------------
__global__ void pack_w2(const float* __restrict__ attn_W, short* __restrict__ Bp)
{
    const int c    = blockIdx.x * 256 + threadIdx.x;       // 32768 chunks
    const int lane = c & 63;
    const int nf   = (c >> 6) & 1;
    const int w    = (c >> 7) & 15;
    const int kk   = c >> 11;                              // 0..15
    const int col  = w * 32 + nf * 16 + (lane & 15);
    const int k    = kk * 32 + (lane >> 4) * 8;
    cvt8(Bp + (size_t)c * 8, attn_W + (size_t)col * (2 * H_) + H_ + k);
}

// ---------------------------------------------------------------------------
// bias1: h @ W1^T + attn_b.  128 blocks x 512 thr, 2 batches per block.
// ---------------------------------------------------------------------------
__global__ void bias1_kernel(const float* __restrict__ hidden,
                             const float* __restrict__ attn_W,
                             const float* __restrict__ attn_b,
                             float* __restrict__ bias1)
{
    const int t  = threadIdx.x;                // output col
    const int b0 = blockIdx.x * 2;
    __shared__ float h_s[2][512];
    h_s[0][t] = hidden[(size_t)b0 * H_ + t];
    h_s[1][t] = hidden[(size_t)(b0 + 1) * H_ + t];
    __syncthreads();
    const float* wrow = attn_W + (size_t)t * (2 * H_);     // W1 part: cols 0..511
    float a0 = 0.f, a1 = 0.f;
#pragma unroll 4
    for (int k = 0; k < 512; k += 4) {
        f32x4_t wv = *(const f32x4_t*)(wrow + k);
        a0 = fmaf(wv[0], h_s[0][k],     a0);
        a0 = fmaf(wv[1], h_s[0][k + 1], a0);
        a0 = fmaf(wv[2], h_s[0][k + 2], a0);
        a0 = fmaf(wv[3], h_s[0][k + 3], a0);
        a1 = fmaf(wv[0], h_s[1][k],     a1);
        a1 = fmaf(wv[1], h_s[1][k + 1], a1);
        a1 = fmaf(wv[2], h_s[1][k + 2], a1);
        a1 = fmaf(wv[3], h_s[1][k + 3], a1);
    }
    const float bb = attn_b[t];
    bias1[(size_t)b0 * H_ + t]       = a0 + bb;
    bias1[(size_t)(b0 + 1) * H_ + t] = a1 + bb;
}

// ---------------------------------------------------------------------------
// fused_attn: 256 blocks x 1024 threads (16 waves). One full batch per block.
// 1024-thread block = occupancy mechanism: 16 waves atomic -> 4 waves/SIMD
// co-resident, backend must fit <=128 VGPR (no attribute games - those
// squeezed to 64 VGPR + scratch spills in rounds 4/5/7).
// VALU-lean inner loop (round 9): A-fragment LDS addresses strength-reduced
//   physc(kk*4+hi, rl) = ((kk&1)<<5) + (hi<<3) + ((kk>>1)^(rl&7))
// so per kk2 ONE xor+shl+add; the 8 ds_read_b128 use immediate offsets
// (mf*16384[+512] B, fits 16-bit DS offset). B = bf16 fragments via saddr
// (reverted from fp8: VALU was the bound at 40% busy, L2 was ~15%).
// Staging converts with packed v_cvt_pk_bf16_f32; tanh = 5-inst rcp form.
// ---------------------------------------------------------------------------
__global__ __launch_bounds__(1024)
void fused_attn(const float* __restrict__ enc,
                const short* __restrict__ Bp,
                const float* __restrict__ bias1,
                const float* __restrict__ vvec,
                float* __restrict__ out_attn,
                short* __restrict__ x_cat)
{
    __shared__ short buf[2][64 * 512];       // 2 x 64 KB, swizzled chunks
    __shared__ float bias_s[512];
    __shared__ float v_s[512];
    __shared__ float e_all[512];
    __shared__ float red[64][17];
    __shared__ float ctx_s[512];
    __shared__ float wred[8];
    __shared__ float l_sh;

    const int t    = threadIdx.x;
    const int lane = t & 63;
    const int w    = t >> 6;                 // 0..15, col group (32 cols)
    const int b    = blockIdx.x;

    if (t < 512) {
        bias_s[t] = bias1[(size_t)b * H_ + t];
        v_s[t]    = vvec[t];
    }

    // staging: row srow (0..63), slot sc (0..15) -> chunks sc + i*16, i=0..3
    const int srow = t >> 4;
    const int sc   = t & 15;
    const float* gbase = enc + ((size_t)b * S_ + srow) * H_ + sc * 8;

    // ctx: chunk cc = t>>4 (0..63), row residue rg = t&15 (rows rg + 16i)
    const int cc = t >> 4;
    const int rg = t & 15;
    float acc8[8];
#pragma unroll
    for (int j = 0; j < 8; ++j) acc8[j] = 0.f;

    // GEMM per-thread constants
    const int l15 = lane & 15;
    const int hi  = lane >> 4;               // 0..3
    const int Y   = l15 & 7;

    // prologue: stage tile 0 into buf[0]
#pragma unroll
    for (int i = 0; i < 4; ++i) {
        const float* sp = gbase + i * 16 * 8;
        f32x4_t a = *(const f32x4_t*)(sp);
        f32x4_t c = *(const f32x4_t*)(sp + 4);
        *(bf16x8_t*)&buf[0][srow * 512 + physc(sc + i * 16, srow) * 8] = pack8(a, c);
    }
    __syncthreads();

    int cur = 0;
    for (int tile = 0; tile < 8; ++tile) {
        // ---- stage tile+1 into buf[cur^1] (last read 1 barrier-epoch ago)
        if (tile < 7) {
            const float* gp = gbase + (size_t)(tile + 1) * 64 * H_;
#pragma unroll
            for (int i = 0; i < 4; ++i) {
                const float* sp = gp + i * 16 * 8;
                f32x4_t a = *(const f32x4_t*)(sp);
                f32x4_t c = *(const f32x4_t*)(sp + 4);
                *(bf16x8_t*)&buf[cur ^ 1][srow * 512 + physc(sc + i * 16, srow) * 8] = pack8(a, c);
            }
        }

        // ---- energy GEMM on buf[cur]: 64 rows x 32 cols (this wave) x K=512
        const short* bufc = buf[cur];
        const short* abase = bufc + l15 * 512 + hi * 64;       // + mf*8192 imm
        const short* bbase = Bp + (size_t)w * 1024 + lane * 8; // + kk*16384 + nf*512

        f32x4_t acc[4][2];
#pragma unroll
        for (int mf = 0; mf < 4; ++mf) {
            acc[mf][0] = (f32x4_t){0.f, 0.f, 0.f, 0.f};
            acc[mf][1] = (f32x4_t){0.f, 0.f, 0.f, 0.f};
        }

#pragma unroll
        for (int kk2 = 0; kk2 < 8; ++kk2) {
            const short* ap  = abase + ((kk2 ^ Y) << 3);
            const short* bp0 = bbase + (size_t)(2 * kk2) * 16384;
            bf16x8_t b00 = *(const bf16x8_t*)(bp0);
            bf16x8_t b01 = *(const bf16x8_t*)(bp0 + 512);
            bf16x8_t b10 = *(const bf16x8_t*)(bp0 + 16384);
            bf16x8_t b11 = *(const bf16x8_t*)(bp0 + 16384 + 512);
            bf16x8_t a0[4], a1[4];
#pragma unroll
            for (int mf = 0; mf < 4; ++mf) {
                a0[mf] = *(const bf16x8_t*)(ap + mf * 8192);
                a1[mf] = *(const bf16x8_t*)(ap + mf * 8192 + 256);
            }
            __builtin_amdgcn_s_setprio(1);
#pragma unroll
            for (int mf = 0; mf < 4; ++mf) {
                acc[mf][0] = __builtin_amdgcn_mfma_f32_16x16x32_bf16(a0[mf], b00, acc[mf][0], 0, 0, 0);
                acc[mf][1] = __builtin_amdgcn_mfma_f32_16x16x32_bf16(a0[mf], b01, acc[mf][1], 0, 0, 0);
            }
#pragma unroll
            for (int mf = 0; mf < 4; ++mf) {
                acc[mf][0] = __builtin_amdgcn_mfma_f32_16x16x32_bf16(a1[mf], b10, acc[mf][0], 0, 0, 0);
                acc[mf][1] = __builtin_amdgcn_mfma_f32_16x16x32_bf16(a1[mf], b11, acc[mf][1], 0, 0, 0);
            }
            __builtin_amdgcn_s_setprio(0);
        }

        // ---- epilogue: per-wave partial score over its 32 cols
        float part[16];
#pragma unroll
        for (int i = 0; i < 16; ++i) part[i] = 0.f;
#pragma unroll
        for (int nf = 0; nf < 2; ++nf) {
            const int col = w * 32 + nf * 16 + l15;
            const float bbv = bias_s[col];
            const float vl  = v_s[col];
#pragma unroll
            for (int mf = 0; mf < 4; ++mf)
#pragma unroll
                for (int r = 0; r < 4; ++r)
                    part[mf * 4 + r] += vl * tanh5(acc[mf][nf][r] + bbv);
        }
#pragma unroll
        for (int i = 0; i < 16; ++i) {
            float p = part[i];
            p += __shfl_xor(p, 1);
            p += __shfl_xor(p, 2);
            p += __shfl_xor(p, 4);
            p += __shfl_xor(p, 8);
            part[i] = p;
        }
        if (l15 == 0) {
#pragma unroll
            for (int mf = 0; mf < 4; ++mf)
#pragma unroll
                for (int r = 0; r < 4; ++r)
                    red[mf * 16 + (hi << 2) + r][w] = part[mf * 4 + r];
        }
        __syncthreads();                      // B1: red + staging writes done

        if (t < 64) {
            float s = 0.f;
#pragma unroll
            for (int g = 0; g < 16; ++g) s += red[t][g];
            e_all[tile * 64 + t] = __expf(s);
        }
        __syncthreads();                      // B2: e_all visible

        // ---- context accumulate from bufc: rows rg+16i, chunk cc
#pragma unroll
        for (int i = 0; i < 4; ++i) {
            const int r   = i * 16 + rg;
            const float e = e_all[tile * 64 + r];
            bf16x8_t ch = *(const bf16x8_t*)&bufc[r * 512 + physc(cc, r) * 8];
#pragma unroll
            for (int j = 0; j < 8; ++j)
                acc8[j] = fmaf(e, bf2f(ch[j]), acc8[j]);
        }
        __syncthreads();                      // B3: ctx reads done (next stage overwrites)
        cur ^= 1;
    }

    // ---- finalize: reduce ctx over the 16 threads sharing chunk cc
#pragma unroll
    for (int m = 1; m < 16; m <<= 1)
#pragma unroll
        for (int j = 0; j < 8; ++j)
            acc8[j] += __shfl_xor(acc8[j], m);
#pragma unroll
    for (int j = 0; j < 8; ++j)
        if (rg == j) ctx_s[cc * 8 + j] = acc8[j];

    // l = sum(e_all)
    if (t < 512) {
        float sv = e_all[t];
#pragma unroll
        for (int off = 32; off; off >>= 1) sv += __shfl_xor(sv, off);
        if (lane == 0) wred[w] = sv;
    }
    __syncthreads();
    if (t == 0) {
        l_sh = wred[0] + wred[1] + wred[2] + wred[3]
             + wred[4] + wred[5] + wred[6] + wred[7];
    }
    __syncthreads();
    if (t < 512) {
        const float li = 1.f / l_sh;
        out_attn[(size_t)b * S_ + t] = e_all[t] * li;
        x_cat[(size_t)b * 1280 + 256 + t] = pack8((f32x4_t){ctx_s[t] * li, 0, 0, 0},
                                                  (f32x4_t){0, 0, 0, 0})[0];
    }
}

// ---------------------------------------------------------------------------
// gemm_std: BM=128, BN=128, BK=32, 4 waves (256 thr). A is pre-converted bf16.
// KIND 0 (gates): K=1280, N=2048, B = [W_ih | W_hh] rows, bias = b_ih+b_hh
// KIND 1 (pred):  K=512,  N=16000, B = fc_W rows,        bias = fc_b
// ---------------------------------------------------------------------------
template<int KIND>
__global__ __launch_bounds__(256, 2)
void gemm_std(const short* __restrict__ Abf,
              const float* __restrict__ B0,
              const float* __restrict__ B1,
              const float* __restrict__ bias0,
              const float* __restrict__ bias1v,
              float* __restrict__ out)
{
    constexpr int K = (KIND == 0) ? 1280 : 512;
    constexpr int N = (KIND == 0) ? 2048 : 16000;

    __shared__ short As[128 * 40];
    __shared__ short Bs[128 * 40];

    const int t    = threadIdx.x;
    const int lane = t & 63;
    const int w    = t >> 6;
    const int wm   = w >> 1;
    const int wn   = w & 1;
    const int row0 = blockIdx.x * 128;
    const int col0 = blockIdx.y * 128;

    f32x4_t acc[4][4];
#pragma unroll
    for (int i = 0; i < 4; ++i)
#pragma unroll
        for (int j = 0; j < 4; ++j)
            acc[i][j] = (f32x4_t){0.f, 0.f, 0.f, 0.f};

    const int arow = t >> 1, ah = (t & 1) * 16;
    const int bcol = t >> 1, bh = (t & 1) * 16;

    for (int ks = 0; ks < K / 32; ++ks) {
        const int k0 = ks * 32;
        __syncthreads();
        const short* asrc = Abf + (size_t)(row0 + arow) * K + k0 + ah;
        *(bf16x8_t*)&As[arow * 40 + ah]     = *(const bf16x8_t*)asrc;
        *(bf16x8_t*)&As[arow * 40 + ah + 8] = *(const bf16x8_t*)(asrc + 8);
        const float* bsrc;
        if constexpr (KIND == 0) {
            const int cg = col0 + bcol;
            bsrc = (k0 < 768) ? (B0 + (size_t)cg * 768 + k0 + bh)
                              : (B1 + (size_t)cg * 512 + (k0 - 768) + bh);
        } else {
            bsrc = B0 + (size_t)(col0 + bcol) * 512 + k0 + bh;
        }
        cvt8(&Bs[bcol * 40 + bh],     bsrc);
        cvt8(&Bs[bcol * 40 + bh + 8], bsrc + 8);
        __syncthreads();

        bf16x8_t af[4], bfr[4];
        const int ka = (lane >> 4) * 8;
#pragma unroll
        for (int mf = 0; mf < 4; ++mf)
            af[mf] = *(const bf16x8_t*)&As[(wm * 64 + mf * 16 + (lane & 15)) * 40 + ka];
#pragma unroll
        for (int nf = 0; nf < 4; ++nf)
            bfr[nf] = *(const bf16x8_t*)&Bs[(wn * 64 + nf * 16 + (lane & 15)) * 40 + ka];
#pragma unroll
        for (int mf = 0; mf < 4; ++mf)
#pragma unroll
            for (int nf = 0; nf < 4; ++nf)
                acc[mf][nf] = __builtin_amdgcn_mfma_f32_16x16x32_bf16(
                    af[mf], bfr[nf], acc[mf][nf], 0, 0, 0);
    }

#pragma unroll
    for (int mf = 0; mf < 4; ++mf)
#pragma unroll
        for (int nf = 0; nf < 4; ++nf) {
            const int col  = col0 + wn * 64 + nf * 16 + (lane & 15);
            const int rowb = row0 + wm * 64 + mf * 16 + ((lane >> 4) << 2);
            float bb;
            if constexpr (KIND == 0) bb = bias0[col] + bias1v[col];
            else                     bb = bias0[col];
#pragma unroll
            for (int r = 0; r < 4; ++r)
                out[(size_t)(rowb + r) * N + col] = acc[mf][nf][r] + bb;
        }
}

// ---------------------------------------------------------------------------
// small kernels
// ---------------------------------------------------------------------------
__global__ void prep_kernel(const int* __restrict__ tgt,
                            const float* __restrict__ emb,
                            const float* __restrict__ hidden,
                            short* __restrict__ x_cat)
{
    const int b = blockIdx.x, t = threadIdx.x;          // 256 threads
    const int tok = tgt[b];
    union { float f; unsigned u; } v0, v1, v2;
    v0.f = emb[(size_t)tok * E_ + t];
    v1.f = hidden[(size_t)b * H_ + t];
    v2.f = hidden[(size_t)b * H_ + 256 + t];
    unsigned r0 = v0.u + 0x7fffu + ((v0.u >> 16) & 1u);
    unsigned r1 = v1.u + 0x7fffu + ((v1.u >> 16) & 1u);
    unsigned r2 = v2.u + 0x7fffu + ((v2.u >> 16) & 1u);
    x_cat[(size_t)b * 1280 + t]             = (short)(r0 >> 16);
    x_cat[(size_t)b * 1280 + 768 + t]       = (short)(r1 >> 16);
    x_cat[(size_t)b * 1280 + 768 + 256 + t] = (short)(r2 >> 16);
}

__global__ void lstm_kernel(const float* __restrict__ gates,
                            const float* __restrict__ cell,
                            float* __restrict__ out_h,
                            float* __restrict__ out_c,
                            short* __restrict__ h_bf)
{
    const int b = blockIdx.x, t = threadIdx.x;          // 512 threads
    const float* g = gates + (size_t)b * 2048;
    const float gi = g[t], gf = g[512 + t], gg = g[1024 + t], go = g[1536 + t];
    const float c  = cell[(size_t)b * H_ + t];
    const float si = 1.f / (1.f + __expf(-gi));
    const float sf = 1.f / (1.f + __expf(-gf));
    const float so = 1.f / (1.f + __expf(-go));
    const float cn = sf * c + si * tanhf(gg);
    const float hn = so * tanhf(cn);
    out_h[(size_t)b * H_ + t] = hn;
    out_c[(size_t)b * H_ + t] = cn;
    union { float f; unsigned u; } v; v.f = hn;
    unsigned r = v.u + 0x7fffu + ((v.u >> 16) & 1u);
    h_bf[(size_t)b * H_ + t]  = (short)(r >> 16);
}

// ---------------------------------------------------------------------------
extern "C" void kernel_launch(void* const* d_in, const int* in_sizes, int n_in,
                              void* d_out, int out_size, void* d_ws, size_t ws_size,
                              hipStream_t stream)
{
    (void)in_sizes; (void)n_in; (void)out_size; (void)ws_size;

    const int*   tgt    = (const int*)d_in[0];
    const float* hidden = (const float*)d_in[1];
    const float* cell   = (const float*)d_in[2];
    const float* enc    = (const float*)d_in[3];
    const float* emb    = (const float*)d_in[4];
    const float* attn_W = (const float*)d_in[5];
    const float* attn_b = (const float*)d_in[6];
    const float* vv     = (const float*)d_in[7];
    const float* W_ih   = (const float*)d_in[8];
    const float* W_hh   = (const float*)d_in[9];
    const float* b_ih   = (const float*)d_in[10];
    const float* b_hh   = (const float*)d_in[11];
    const float* fc_W   = (const float*)d_in[12];
    const float* fc_b   = (const float*)d_in[13];

    float* out_pred = (float*)d_out;                       // [256][16000]
    float* out_h    = out_pred + (size_t)B_ * V_;          // [256][512]
    float* out_c    = out_h + (size_t)B_ * H_;             // [256][512]
    float* out_attn = out_c + (size_t)B_ * H_;             // [256][512]

    char*  ws      = (char*)d_ws;
    float* bias1   = (float*)ws;                           // 131072 f32
    float* gates   = bias1 + (size_t)B_ * H_;              // 524288 f32
    short* x_cat   = (short*)(gates + (size_t)B_ * 2048);  // 327680 bf16
    short* h_bf    = x_cat + (size_t)B_ * 1280;            // 131072 bf16
    short* b2p     = h_bf + (size_t)B_ * H_;               // 262144 bf16 packed

    // 0. pack W2 half into fragment-ordered bf16
    pack_w2<<<128, 256, 0, stream>>>(attn_W, b2p);
    // 1. embedding gather + h into x_cat (bf16)
    prep_kernel<<<B_, 256, 0, stream>>>(tgt, emb, hidden, x_cat);
    // 2. bias1 = h @ W1^T + attn_b
    bias1_kernel<<<128, 512, 0, stream>>>(hidden, attn_W, attn_b, bias1);
    // 3. fused attention: scores + softmax + context, enc read once
    fused_attn<<<B_, 1024, 0, stream>>>(enc, b2p, bias1, vv, out_attn, x_cat);
    // 4. gates = x_cat @ [W_ih|W_hh]^T + b_ih + b_hh
    gemm_std<0><<<dim3(2, 16), 256, 0, stream>>>(x_cat, W_ih, W_hh, b_ih, b_hh, gates);
    // 5. LSTM pointwise
    lstm_kernel<<<B_, 512, 0, stream>>>(gates, cell, out_h, out_c, h_bf);
    // 6. prediction = h_new @ fc_W^T + fc_b
    gemm_std<1><<<dim3(2, 125), 256, 0, stream>>>(h_bf, fc_W, nullptr, fc_b, nullptr, out_pred);
}